// Round 8
// baseline (503.174 us; speedup 1.0000x reference)
//
#include <hip/hip_runtime.h>
#include <float.h>
#include <math.h>

// Problem constants (reference: B=4, N=4096, DIM_IN=DIM_INNER=DIM_OUT=512)
#define B_    4
#define N_    4096
#define DIN   512
#define DI    512      // dim_inner
#define DOUTD 512      // dim_out
#define DQKV  1536     // 3*dim_inner
#define MTOT  (B_*N_)  // 16384

static constexpr float kScale  = 0.044194173824159216f;  // 512^-0.5
// Masked sentinel: finite in bf16 (see R1 post-mortem); exp() underflows to 0.
static constexpr float kNegMax = -3.0e38f;

typedef float f32x4  __attribute__((ext_vector_type(4)));
typedef short bf16x8 __attribute__((ext_vector_type(8)));   // 8 bf16 in 4 VGPRs

__device__ __forceinline__ unsigned short f2b(float f) {
    unsigned u = __builtin_bit_cast(unsigned, f);
    unsigned r = (u + 0x7fffu + ((u >> 16) & 1u)) >> 16;    // RNE
    return (unsigned short)r;
}

// ---------------------------------------------------------------------------
// Swizzled [rows][64 cols] bf16 LDS tile: row stride 128B (8 slots of 16B),
// slot ^= (row & 7).  T14 split: ldreg_* issues global loads early;
// streg_* writes LDS late, so HBM latency hides under compute.
// ---------------------------------------------------------------------------
__device__ __forceinline__ void ldreg_b16(bf16x8 v[4], const short* src,
                                          int srcStride, int k0)
{
    int t = threadIdx.x;
    int r = t >> 1, h = t & 1;
    const short* p = src + (size_t)r * srcStride + k0 + h * 32;
    #pragma unroll
    for (int q = 0; q < 4; ++q) v[q] = *reinterpret_cast<const bf16x8*>(p + q * 8);
}

__device__ __forceinline__ void streg_b16(short* lds, const bf16x8 v[4])
{
    int t = threadIdx.x;
    int r = t >> 1, h = t & 1;
    #pragma unroll
    for (int q = 0; q < 4; ++q) {
        int slot = (h * 4 + q) ^ (r & 7);
        *reinterpret_cast<bf16x8*>(&lds[r * 64 + slot * 8]) = v[q];
    }
}

__device__ __forceinline__ void ldreg_f32(f32x4 v[8], const float* src,
                                          int srcStride, int k0)
{
    int t = threadIdx.x;
    int r = t >> 1, h = t & 1;
    const float* p = src + (size_t)r * srcStride + k0 + h * 32;
    #pragma unroll
    for (int q = 0; q < 8; ++q) v[q] = *reinterpret_cast<const f32x4*>(p + q * 4);
}

__device__ __forceinline__ void streg_f32(short* lds, const f32x4 v[8])
{
    int t = threadIdx.x;
    int r = t >> 1, h = t & 1;
    #pragma unroll
    for (int q = 0; q < 4; ++q) {
        bf16x8 w;
        w[0] = (short)f2b(v[2 * q][0]); w[1] = (short)f2b(v[2 * q][1]);
        w[2] = (short)f2b(v[2 * q][2]); w[3] = (short)f2b(v[2 * q][3]);
        w[4] = (short)f2b(v[2 * q + 1][0]); w[5] = (short)f2b(v[2 * q + 1][1]);
        w[6] = (short)f2b(v[2 * q + 1][2]); w[7] = (short)f2b(v[2 * q + 1][3]);
        int slot = (h * 4 + q) ^ (r & 7);
        *reinterpret_cast<bf16x8*>(&lds[r * 64 + slot * 8]) = w;
    }
}

__device__ __forceinline__ bf16x8 ld_frag(const short* lds, int rowbase, int kk)
{
    int l = threadIdx.x & 63;
    int r = rowbase + (l & 15);
    int slot = (kk * 4 + (l >> 4)) ^ (r & 7);
    return *reinterpret_cast<const bf16x8*>(&lds[r * 64 + slot * 8]);
}

// ---------------------------------------------------------------------------
// Weight transpose-convert: W [K][N] f32 -> Wt [N][K] bf16.  grid(N/64, K/64)
// ---------------------------------------------------------------------------
__global__ __launch_bounds__(256)
void cvt_wt(const float* __restrict__ W, short* __restrict__ Wt, int K, int N)
{
    __shared__ float t[64][65];
    const int n0 = blockIdx.x * 64, k0 = blockIdx.y * 64;
    const int tid = threadIdx.x;
    #pragma unroll
    for (int q = 0; q < 4; ++q) {
        int r = (tid >> 4) + q * 16, c4 = (tid & 15) * 4;
        float4 f = *reinterpret_cast<const float4*>(&W[(size_t)(k0 + r) * N + n0 + c4]);
        t[r][c4] = f.x; t[r][c4 + 1] = f.y; t[r][c4 + 2] = f.z; t[r][c4 + 3] = f.w;
    }
    __syncthreads();
    #pragma unroll
    for (int p = 0; p < 2; ++p) {
        int s = tid * 2 + p;
        int n = s >> 3, k8 = (s & 7) * 8;
        bf16x8 v;
        #pragma unroll
        for (int e = 0; e < 8; ++e) v[e] = (short)f2b(t[k8 + e][n]);
        *reinterpret_cast<bf16x8*>(&Wt[(size_t)(n0 + n) * K + k0 + k8]) = v;
    }
}

// ---------------------------------------------------------------------------
// Generic bf16-MFMA GEMM: C[M][Nld] = A[M][K] @ Bt[N][K]^T (+bias).
// 128x128 tile, 4 waves (2x2), BK=64, compile-time K (full unroll).
// Operand-SWAPPED mfma: lane owns an output ROW, regs = 4 consecutive cols.
// No setprio (lockstep schedule - m190).
// ---------------------------------------------------------------------------
template<int K, bool AF32, bool OUTF32, bool BIAS>
__global__ __launch_bounds__(256)
void gemm_mfma(const void* __restrict__ Ap, const short* __restrict__ Bt,
               const float* __restrict__ bias, void* __restrict__ Cp,
               int Nld)
{
    const int bm = blockIdx.y * 128;
    const int bn = blockIdx.x * 128;
    __shared__ short As[128 * 64];
    __shared__ short Bs[128 * 64];
    const int tid = threadIdx.x, lane = tid & 63, wid = tid >> 6;
    const int wr = (wid >> 1) * 64, wc = (wid & 1) * 64;
    f32x4 acc[4][4] = {};

    const float* Af = (const float*)Ap + (size_t)bm * K;
    const short* Ab = (const short*)Ap + (size_t)bm * K;
    const short* Bb = Bt + (size_t)bn * K;

    bf16x8 av[4]; f32x4 af[8]; bf16x8 bv[4];
    if (AF32) ldreg_f32(af, Af, K, 0); else ldreg_b16(av, Ab, K, 0);
    ldreg_b16(bv, Bb, K, 0);

    #pragma unroll
    for (int kt = 0; kt < K / 64; ++kt) {
        if (AF32) streg_f32(As, af); else streg_b16(As, av);
        streg_b16(Bs, bv);
        __syncthreads();
        if (kt + 1 < K / 64) {      // issue next-tile loads; land under MFMA
            if (AF32) ldreg_f32(af, Af, K, (kt + 1) * 64);
            else      ldreg_b16(av, Ab, K, (kt + 1) * 64);
            ldreg_b16(bv, Bb, K, (kt + 1) * 64);
        }
        #pragma unroll
        for (int kk = 0; kk < 2; ++kk) {
            bf16x8 a[4], bb[4];
            #pragma unroll
            for (int m = 0; m < 4; ++m) a[m] = ld_frag(As, wr + m * 16, kk);
            #pragma unroll
            for (int n = 0; n < 4; ++n) bb[n] = ld_frag(Bs, wc + n * 16, kk);
            #pragma unroll
            for (int m = 0; m < 4; ++m)
                #pragma unroll
                for (int n = 0; n < 4; ++n)   // SWAPPED
                    acc[m][n] = __builtin_amdgcn_mfma_f32_16x16x32_bf16(bb[n], a[m], acc[m][n], 0, 0, 0);
        }
        __syncthreads();
    }
    const int rb = bm + wr + (lane & 15);
    const int cb = bn + wc + (lane >> 4) * 4;
    #pragma unroll
    for (int m = 0; m < 4; ++m) {
        const int row = rb + m * 16;
        #pragma unroll
        for (int n = 0; n < 4; ++n) {
            const int colb = cb + n * 16;
            f32x4 v = acc[m][n];
            if (BIAS) {
                f32x4 bi = *reinterpret_cast<const f32x4*>(&bias[colb]);
                v += bi;
            }
            if (OUTF32) {
                *reinterpret_cast<f32x4*>(&((float*)Cp)[(size_t)row * Nld + colb]) = v;
            } else {
                short4 o;
                o.x = (short)f2b(v[0]); o.y = (short)f2b(v[1]);
                o.z = (short)f2b(v[2]); o.w = (short)f2b(v[3]);
                *reinterpret_cast<short4*>(&((short*)Cp)[(size_t)row * Nld + colb]) = o;
            }
        }
    }
}

// ---------------------------------------------------------------------------
// v cols of qkvb (bf16, col offset 1024) -> Vt bf16 [b][d][n]
// ---------------------------------------------------------------------------
__global__ __launch_bounds__(256)
void cvt_vt(const short* __restrict__ qkvb, short* __restrict__ Vt)
{
    __shared__ short t[64][72];
    const int b = blockIdx.z, n0 = blockIdx.x * 64, d0 = blockIdx.y * 64;
    const int tid = threadIdx.x;
    const short* src = qkvb + (size_t)(b * N_ + n0) * DQKV + 2 * DI + d0;
    #pragma unroll
    for (int q = 0; q < 2; ++q) {
        int s = tid + q * 256;
        int n = s >> 3, d8 = (s & 7) * 8;
        bf16x8 v = *reinterpret_cast<const bf16x8*>(&src[(size_t)n * DQKV + d8]);
        #pragma unroll
        for (int e = 0; e < 8; ++e) t[n][d8 + e] = v[e];
    }
    __syncthreads();
    short* dst = Vt + (size_t)b * DI * N_;
    #pragma unroll
    for (int q = 0; q < 2; ++q) {
        int s = tid + q * 256;
        int d = s >> 3, n8 = (s & 7) * 8;
        bf16x8 v;
        #pragma unroll
        for (int e = 0; e < 8; ++e) v[e] = t[n8 + e][d];
        *reinterpret_cast<bf16x8*>(&dst[(size_t)(d0 + d) * N_ + n0 + n8]) = v;
    }
}

// ---------------------------------------------------------------------------
// sim = q k^T * scale + prev, causal-masked, with fused per-128-block softmax
// partials -> Pm/Pl [b][jT][i].  DEPTH-2 register prefetch: loads for tile
// kt+2 are issued at iter kt, giving ~2 MFMA phases + barriers of latency
// cover (vs ~1 phase at depth-1).  Fully unrolled (8 iters) so the [kt&1]
// staging-set index is compile-time (rule #20).  No setprio.
// grid: (N/128 j, N/128 i, B)
// ---------------------------------------------------------------------------
__global__ __launch_bounds__(256)
void sim_mfma(const short* __restrict__ qkvb, const float* __restrict__ prev,
              float* __restrict__ sim, float* __restrict__ Pm, float* __restrict__ Pl)
{
    const int b  = blockIdx.z;
    const int i0 = blockIdx.y * 128;
    const int j0 = blockIdx.x * 128;
    const int tid = threadIdx.x;
    float* simb = sim + (size_t)b * N_ * N_;

    if (j0 > i0 + 127) {                    // fully-masked: fill (no partials)
        const float4 m4 = make_float4(kNegMax, kNegMax, kNegMax, kNegMax);
        #pragma unroll
        for (int l = 0; l < 16; ++l) {
            int idx = tid + l * 256;
            int r = idx >> 5, c = (idx & 31) * 4;
            *reinterpret_cast<float4*>(&simb[(size_t)(i0 + r) * N_ + (j0 + c)]) = m4;
        }
        return;
    }

    __shared__ short Qs[128 * 64];
    __shared__ short Ks[128 * 64];
    __shared__ float wm[2][128], wl[2][128];
    const short* qb = qkvb + (size_t)(b * N_ + i0) * DQKV;
    const short* kb = qkvb + (size_t)(b * N_ + j0) * DQKV + DI;
    const int lane = tid & 63, wid = tid >> 6;
    const int wr = (wid >> 1) * 64, wc = (wid & 1) * 64;
    f32x4 acc[4][4] = {};

    bf16x8 qv[2][4], kv[2][4];
    ldreg_b16(qv[0], qb, DQKV, 0);
    ldreg_b16(kv[0], kb, DQKV, 0);
    ldreg_b16(qv[1], qb, DQKV, 64);
    ldreg_b16(kv[1], kb, DQKV, 64);

    #pragma unroll
    for (int kt = 0; kt < 8; ++kt) {        // constant trip -> full unroll
        streg_b16(Qs, qv[kt & 1]);
        streg_b16(Ks, kv[kt & 1]);
        __syncthreads();
        if (kt + 2 < 8) {                   // issue tile kt+2 into the set just freed
            ldreg_b16(qv[kt & 1], qb, DQKV, (kt + 2) * 64);
            ldreg_b16(kv[kt & 1], kb, DQKV, (kt + 2) * 64);
        }
        #pragma unroll
        for (int kk = 0; kk < 2; ++kk) {
            bf16x8 a[4], bb[4];
            #pragma unroll
            for (int m = 0; m < 4; ++m) a[m] = ld_frag(Qs, wr + m * 16, kk);
            #pragma unroll
            for (int n = 0; n < 4; ++n) bb[n] = ld_frag(Ks, wc + n * 16, kk);
            #pragma unroll
            for (int m = 0; m < 4; ++m)
                #pragma unroll
                for (int n = 0; n < 4; ++n)   // SWAPPED
                    acc[m][n] = __builtin_amdgcn_mfma_f32_16x16x32_bf16(bb[n], a[m], acc[m][n], 0, 0, 0);
        }
        __syncthreads();
    }
    const float* prevb = prev + (size_t)b * N_ * N_;
    const int ib = i0 + wr + (lane & 15);
    const int jb = j0 + wc + (lane >> 4) * 4;
    const int wcIdx = wid & 1;
    #pragma unroll
    for (int m = 0; m < 4; ++m) {
        const int row = ib + m * 16;
        float mx = -FLT_MAX;
        f32x4 ovals[4];
        #pragma unroll
        for (int n = 0; n < 4; ++n) {
            const int colb = jb + n * 16;
            f32x4 p = *reinterpret_cast<const f32x4*>(&prevb[(size_t)row * N_ + colb]);
            f32x4 o;
            #pragma unroll
            for (int reg = 0; reg < 4; ++reg)
                o[reg] = (colb + reg <= row) ? fmaf(acc[m][n][reg], kScale, p[reg]) : kNegMax;
            *reinterpret_cast<f32x4*>(&simb[(size_t)row * N_ + colb]) = o;
            ovals[n] = o;
            #pragma unroll
            for (int reg = 0; reg < 4; ++reg) mx = fmaxf(mx, o[reg]);
        }
        mx = fmaxf(mx, __shfl_xor(mx, 16));
        mx = fmaxf(mx, __shfl_xor(mx, 32));
        float s = 0.f;
        #pragma unroll
        for (int n = 0; n < 4; ++n)
            #pragma unroll
            for (int reg = 0; reg < 4; ++reg) s += __expf(ovals[n][reg] - mx);
        s += __shfl_xor(s, 16);
        s += __shfl_xor(s, 32);
        if ((lane >> 4) == 0) {
            int rr = wr + m * 16 + (lane & 15);
            wm[wcIdx][rr] = mx;
            wl[wcIdx][rr] = s;
        }
    }
    __syncthreads();
    if (tid < 128) {
        float m0 = wm[0][tid], m1 = wm[1][tid];
        float l0 = wl[0][tid], l1 = wl[1][tid];
        float M, L;
        if (m1 <= -1.0e38f) { M = m0; L = l0; }
        else {
            M = fmaxf(m0, m1);
            L = l0 * __expf(m0 - M) + l1 * __expf(m1 - M);
        }
        size_t slot = ((size_t)b * 32 + (j0 >> 7)) * N_ + i0 + tid;
        Pm[slot] = M;
        Pl[slot] = L;
    }
}

// ---------------------------------------------------------------------------
// Merge per-block partials into rowM / rowInv.
// ---------------------------------------------------------------------------
__global__ __launch_bounds__(256)
void merge_stats(const float* __restrict__ Pm, const float* __restrict__ Pl,
                 float* __restrict__ rowM, float* __restrict__ rowInv)
{
    int gid = blockIdx.x * 256 + threadIdx.x;        // 0..16383
    int b = gid >> 12, i = gid & (N_ - 1);
    int nt = (i >> 7) + 1;
    const float* pm = Pm + (size_t)b * 32 * N_ + i;
    const float* pl = Pl + (size_t)b * 32 * N_ + i;
    float M = -FLT_MAX;
    for (int t = 0; t < nt; ++t) M = fmaxf(M, pm[(size_t)t * N_]);
    float L = 0.f;
    for (int t = 0; t < nt; ++t) L += pl[(size_t)t * N_] * __expf(pm[(size_t)t * N_] - M);
    rowM[gid] = M;
    rowInv[gid] = 1.0f / L;
}

// ---------------------------------------------------------------------------
// Two-pass PV: out0b = softmax(sim) @ v with precomputed (M, 1/L).
// Block = 64 i x 256 d, 4 waves along d.  Register double-buffered prefetch.
// LPT grid: biggest i-tiles first.  No setprio.
// ---------------------------------------------------------------------------
__global__ __launch_bounds__(256)
void attn_v2(const float* __restrict__ sim, const short* __restrict__ Vt,
             const float* __restrict__ rowM, const float* __restrict__ rowInv,
             short* __restrict__ out0b)
{
    const int g = blockIdx.x;                 // 0..511, LPT order
    const int iT = 63 - (g >> 3);
    const int b = (g >> 1) & 3, dchunk = g & 1;
    const int i0 = iT * 64, d0 = dchunk * 256;
    const int tid = threadIdx.x;
    const int lane = tid & 63, wid = tid >> 6;
    const int wd = wid * 64;

    __shared__ short Ps[64 * 64];
    __shared__ short Vs[256 * 64];
    __shared__ float rm[64], ri[64];
    if (tid < 64) {
        rm[tid] = rowM[b * N_ + i0 + tid];
        ri[tid] = rowInv[b * N_ + i0 + tid];
    }
    __syncthreads();

    const float* simb = sim + (size_t)b * N_ * N_ + (size_t)i0 * N_;
    const short* vtb  = Vt + (size_t)b * DI * N_ + (size_t)d0 * N_;
    const int pr = tid >> 2, pc = (tid & 3) * 16;
    const float pmr = rm[pr], pir = ri[pr];
    f32x4 acc[4][4] = {};
    const int nk = iT + 1;

    f32x4  svA[4]; bf16x8 vvA[8];
    {
        const float* p = simb + (size_t)pr * N_ + pc;
        #pragma unroll
        for (int q = 0; q < 4; ++q) svA[q] = *reinterpret_cast<const f32x4*>(p + q * 4);
        const short* vp = vtb + (size_t)tid * N_;
        #pragma unroll
        for (int q = 0; q < 8; ++q) vvA[q] = *reinterpret_cast<const bf16x8*>(vp + q * 8);
    }
    for (int kt = 0; kt < nk; ++kt) {
        f32x4  svB[4]; bf16x8 vvB[8];
        const bool more = (kt + 1 < nk);
        if (more) {
            const float* p = simb + (size_t)pr * N_ + (kt + 1) * 64 + pc;
            #pragma unroll
            for (int q = 0; q < 4; ++q) svB[q] = *reinterpret_cast<const f32x4*>(p + q * 4);
            const short* vp = vtb + (size_t)tid * N_ + (kt + 1) * 64;
            #pragma unroll
            for (int q = 0; q < 8; ++q) vvB[q] = *reinterpret_cast<const bf16x8*>(vp + q * 8);
        }
        bf16x8 w0, w1;
        #pragma unroll
        for (int q = 0; q < 2; ++q)
            #pragma unroll
            for (int e = 0; e < 4; ++e) {
                w0[q * 4 + e] = (short)f2b(__expf(svA[q][e] - pmr) * pir);
                w1[q * 4 + e] = (short)f2b(__expf(svA[2 + q][e] - pmr) * pir);
            }
        {
            int sb = (tid & 3) * 2;
            *reinterpret_cast<bf16x8*>(&Ps[pr * 64 + ((sb    ) ^ (pr & 7)) * 8]) = w0;
            *reinterpret_cast<bf16x8*>(&Ps[pr * 64 + ((sb + 1) ^ (pr & 7)) * 8]) = w1;
        }
        #pragma unroll
        for (int q = 0; q < 8; ++q)
            *reinterpret_cast<bf16x8*>(&Vs[tid * 64 + (q ^ (tid & 7)) * 8]) = vvA[q];
        __syncthreads();
        #pragma unroll
        for (int kk = 0; kk < 2; ++kk) {
            bf16x8 a[4], bb[4];
            #pragma unroll
            for (int m = 0; m < 4; ++m) a[m] = ld_frag(Ps, m * 16, kk);
            #pragma unroll
            for (int n = 0; n < 4; ++n) bb[n] = ld_frag(Vs, wd + n * 16, kk);
            #pragma unroll
            for (int m = 0; m < 4; ++m)
                #pragma unroll
                for (int n = 0; n < 4; ++n)
                    acc[m][n] = __builtin_amdgcn_mfma_f32_16x16x32_bf16(bb[n], a[m], acc[m][n], 0, 0, 0);
        }
        __syncthreads();
        if (more) {
            #pragma unroll
            for (int q = 0; q < 4; ++q) svA[q] = svB[q];
            #pragma unroll
            for (int q = 0; q < 8; ++q) vvA[q] = vvB[q];
        }
    }
    #pragma unroll
    for (int m = 0; m < 4; ++m) {
        const int i = i0 + m * 16 + (lane & 15);
        #pragma unroll
        for (int n = 0; n < 4; ++n) {
            const int db = d0 + wd + n * 16 + (lane >> 4) * 4;
            short4 o;
            o.x = (short)f2b(acc[m][n][0]);
            o.y = (short)f2b(acc[m][n][1]);
            o.z = (short)f2b(acc[m][n][2]);
            o.w = (short)f2b(acc[m][n][3]);
            *reinterpret_cast<short4*>(&out0b[(size_t)(b * N_ + i) * DI + db]) = o;
        }
    }
}

// ---------------------------------------------------------------------------
extern "C" void kernel_launch(void* const* d_in, const int* in_sizes, int n_in,
                              void* d_out, int out_size, void* d_ws, size_t ws_size,
                              hipStream_t stream)
{
    (void)in_sizes; (void)n_in; (void)out_size; (void)ws_size;
    const float* x    = (const float*)d_in[0];
    const float* prev = (const float*)d_in[1];
    const float* Wqkv = (const float*)d_in[2];
    const float* Wout = (const float*)d_in[3];
    const float* bout = (const float*)d_in[4];

    float* out = (float*)d_out;                        // [4,4096,512]
    float* sim = out + (size_t)MTOT * DOUTD;           // [4,4096,4096]

    // workspace (~90 MB)
    short* qkvb   = (short*)d_ws;                      // [16384][1536] bf16
    short* out0b  = qkvb + (size_t)MTOT * DQKV;        // [16384][512]  bf16
    short* Vt     = out0b + (size_t)MTOT * DI;         // [4][512][4096] bf16
    short* Wqkvt  = Vt + (size_t)MTOT * DI;            // [1536][512]
    short* Woutt  = Wqkvt + (size_t)DQKV * DIN;        // [512][512]
    float* Pm     = (float*)(Woutt + (size_t)DI * DOUTD);  // [4][32][4096]
    float* Pl     = Pm + (size_t)B_ * 32 * N_;             // [4][32][4096]
    float* rowM   = Pl + (size_t)B_ * 32 * N_;             // [16384]
    float* rowInv = rowM + MTOT;                           // [16384]

    // 0) weight transpose-converts (tiny)
    cvt_wt<<<dim3(DQKV / 64, DIN / 64), 256, 0, stream>>>(Wqkv, Wqkvt, DIN, DQKV);
    cvt_wt<<<dim3(DOUTD / 64, DI / 64), 256, 0, stream>>>(Wout, Woutt, DI, DOUTD);

    // 1) qkvb = bf16(x) @ bf16(Wqkv)   (MFMA, unrolled pipelined staging)
    gemm_mfma<DIN, true, false, false><<<dim3(DQKV / 128, MTOT / 128), 256, 0, stream>>>(
        x, Wqkvt, nullptr, qkvb, DQKV);

    // 2) v -> Vt transposed
    cvt_vt<<<dim3(N_ / 64, DI / 64, B_), 256, 0, stream>>>(qkvb, Vt);

    // 3) sim = q k^T * scale + prev + fused softmax partials (depth-2 prefetch)
    sim_mfma<<<dim3(N_ / 128, N_ / 128, B_), 256, 0, stream>>>(qkvb, prev, sim, Pm, Pl);

    // 4) merge partials -> rowM, rowInv
    merge_stats<<<dim3(MTOT / 256), 256, 0, stream>>>(Pm, Pl, rowM, rowInv);

    // 5) out0b = softmax(sim) @ v   (two-pass PV, prefetched, LPT order)
    attn_v2<<<dim3(512), 256, 0, stream>>>(sim, Vt, rowM, rowInv, out0b);

    // 6) out = out0b @ Wout + bout  (MFMA, f32 out)
    gemm_mfma<DI, false, true, true><<<dim3(DOUTD / 128, MTOT / 128), 256, 0, stream>>>(
        out0b, Woutt, bout, out, DOUTD);
}

// Round 9
// 477.981 us; speedup vs baseline: 1.0527x; 1.0527x over previous
//
#include <hip/hip_runtime.h>
#include <float.h>
#include <math.h>

// Problem constants (reference: B=4, N=4096, DIM_IN=DIM_INNER=DIM_OUT=512)
#define B_    4
#define N_    4096
#define DIN   512
#define DI    512      // dim_inner
#define DOUTD 512      // dim_out
#define DQKV  1536     // 3*dim_inner
#define MTOT  (B_*N_)  // 16384

static constexpr float kScale  = 0.044194173824159216f;  // 512^-0.5
// Masked sentinel: finite in bf16 (see R1 post-mortem); exp() underflows to 0.
static constexpr float kNegMax = -3.0e38f;

typedef float f32x4  __attribute__((ext_vector_type(4)));
typedef short bf16x8 __attribute__((ext_vector_type(8)));   // 8 bf16 in 4 VGPRs

__device__ __forceinline__ unsigned short f2b(float f) {
    unsigned u = __builtin_bit_cast(unsigned, f);
    unsigned r = (u + 0x7fffu + ((u >> 16) & 1u)) >> 16;    // RNE
    return (unsigned short)r;
}

// ---------------------------------------------------------------------------
// Swizzled [rows][64 cols] bf16 LDS tile: row stride 128B (8 slots of 16B),
// LDS slot s of row r holds source chunk g = s ^ (r & 7)  (involution).
//
// gstage_tile: direct global->LDS DMA (global_load_lds, 16B/lane).  LDS dest
// is wave-uniform base + lane*16 (HW rule, m104/m108); the swizzle lives in
// the per-lane SOURCE address (rule #21: linear dest + inverse-swz source).
// Per wave-iteration, chunk c = wbase + lane: r = c>>3, s = lane&7,
// r&7 = lane>>3  ->  g = (lane&7) ^ (lane>>3).
// ---------------------------------------------------------------------------
__device__ __forceinline__ void gstage_tile(short* lds, const short* src,
                                            int srcStride, int k0)
{
    const int tid = threadIdx.x;
    const int w = tid >> 6, lane = tid & 63;
    const int rlo = lane >> 3;                 // r & 7
    const int g   = (lane & 7) ^ rlo;          // source chunk within row
    #pragma unroll
    for (int t = 0; t < 4; ++t) {
        int r = w * 32 + t * 8 + rlo;
        const short* gp = src + (size_t)r * srcStride + k0 + g * 8;
        short* lp = lds + (w * 256 + t * 64) * 8;     // wave-uniform
        __builtin_amdgcn_global_load_lds(
            (const __attribute__((address_space(1))) void*)gp,
            (__attribute__((address_space(3))) void*)lp, 16, 0, 0);
    }
}

// f32 source staged through registers with fused bf16 convert (qkv GEMM A).
__device__ __forceinline__ void ldreg_f32(f32x4 v[8], const float* src,
                                          int srcStride, int k0)
{
    int t = threadIdx.x;
    int r = t >> 1, h = t & 1;
    const float* p = src + (size_t)r * srcStride + k0 + h * 32;
    #pragma unroll
    for (int q = 0; q < 8; ++q) v[q] = *reinterpret_cast<const f32x4*>(p + q * 4);
}

__device__ __forceinline__ void streg_f32(short* lds, const f32x4 v[8])
{
    int t = threadIdx.x;
    int r = t >> 1, h = t & 1;
    #pragma unroll
    for (int q = 0; q < 4; ++q) {
        bf16x8 w;
        w[0] = (short)f2b(v[2 * q][0]); w[1] = (short)f2b(v[2 * q][1]);
        w[2] = (short)f2b(v[2 * q][2]); w[3] = (short)f2b(v[2 * q][3]);
        w[4] = (short)f2b(v[2 * q + 1][0]); w[5] = (short)f2b(v[2 * q + 1][1]);
        w[6] = (short)f2b(v[2 * q + 1][2]); w[7] = (short)f2b(v[2 * q + 1][3]);
        int slot = (h * 4 + q) ^ (r & 7);
        *reinterpret_cast<bf16x8*>(&lds[r * 64 + slot * 8]) = w;
    }
}

__device__ __forceinline__ bf16x8 ld_frag(const short* lds, int rowbase, int kk)
{
    int l = threadIdx.x & 63;
    int r = rowbase + (l & 15);
    int slot = (kk * 4 + (l >> 4)) ^ (r & 7);
    return *reinterpret_cast<const bf16x8*>(&lds[r * 64 + slot * 8]);
}

// ---------------------------------------------------------------------------
// Weight transpose-convert: W [K][N] f32 -> Wt [N][K] bf16.  grid(N/64, K/64)
// ---------------------------------------------------------------------------
__global__ __launch_bounds__(256)
void cvt_wt(const float* __restrict__ W, short* __restrict__ Wt, int K, int N)
{
    __shared__ float t[64][65];
    const int n0 = blockIdx.x * 64, k0 = blockIdx.y * 64;
    const int tid = threadIdx.x;
    #pragma unroll
    for (int q = 0; q < 4; ++q) {
        int r = (tid >> 4) + q * 16, c4 = (tid & 15) * 4;
        float4 f = *reinterpret_cast<const float4*>(&W[(size_t)(k0 + r) * N + n0 + c4]);
        t[r][c4] = f.x; t[r][c4 + 1] = f.y; t[r][c4 + 2] = f.z; t[r][c4 + 3] = f.w;
    }
    __syncthreads();
    #pragma unroll
    for (int p = 0; p < 2; ++p) {
        int s = tid * 2 + p;
        int n = s >> 3, k8 = (s & 7) * 8;
        bf16x8 v;
        #pragma unroll
        for (int e = 0; e < 8; ++e) v[e] = (short)f2b(t[k8 + e][n]);
        *reinterpret_cast<bf16x8*>(&Wt[(size_t)(n0 + n) * K + k0 + k8]) = v;
    }
}

// ---------------------------------------------------------------------------
// Generic bf16-MFMA GEMM: C[M][Nld] = A[M][K] @ Bt[N][K]^T (+bias).
// 128x128 tile, 4 waves (2x2), BK=64.  B (and bf16 A) staged via
// global_load_lds; f32 A staged via registers w/ fused convert (depth-1).
// Operand-SWAPPED mfma: lane owns output ROW, regs = 4 consecutive cols.
// ---------------------------------------------------------------------------
template<int K, bool AF32, bool OUTF32, bool BIAS>
__global__ __launch_bounds__(256)
void gemm_mfma(const void* __restrict__ Ap, const short* __restrict__ Bt,
               const float* __restrict__ bias, void* __restrict__ Cp,
               int Nld)
{
    const int bm = blockIdx.y * 128;
    const int bn = blockIdx.x * 128;
    __shared__ short As[128 * 64];
    __shared__ short Bs[128 * 64];
    const int tid = threadIdx.x, lane = tid & 63, wid = tid >> 6;
    const int wr = (wid >> 1) * 64, wc = (wid & 1) * 64;
    f32x4 acc[4][4] = {};

    const float* Af = (const float*)Ap + (size_t)bm * K;
    const short* Ab = (const short*)Ap + (size_t)bm * K;
    const short* Bb = Bt + (size_t)bn * K;

    f32x4 af[8];
    if (AF32) ldreg_f32(af, Af, K, 0);

    for (int kt = 0; kt < K / 64; ++kt) {
        if (AF32) streg_f32(As, af);
        else      gstage_tile(As, Ab, K, kt * 64);
        gstage_tile(Bs, Bb, K, kt * 64);
        __syncthreads();                       // drains vmcnt + lgkmcnt
        if (AF32 && kt + 1 < K / 64)           // prefetch next A under MFMA
            ldreg_f32(af, Af, K, (kt + 1) * 64);
        #pragma unroll
        for (int kk = 0; kk < 2; ++kk) {
            bf16x8 a[4], bb[4];
            #pragma unroll
            for (int m = 0; m < 4; ++m) a[m] = ld_frag(As, wr + m * 16, kk);
            #pragma unroll
            for (int n = 0; n < 4; ++n) bb[n] = ld_frag(Bs, wc + n * 16, kk);
            #pragma unroll
            for (int m = 0; m < 4; ++m)
                #pragma unroll
                for (int n = 0; n < 4; ++n)   // SWAPPED
                    acc[m][n] = __builtin_amdgcn_mfma_f32_16x16x32_bf16(bb[n], a[m], acc[m][n], 0, 0, 0);
        }
        __syncthreads();
    }
    const int rb = bm + wr + (lane & 15);
    const int cb = bn + wc + (lane >> 4) * 4;
    #pragma unroll
    for (int m = 0; m < 4; ++m) {
        const int row = rb + m * 16;
        #pragma unroll
        for (int n = 0; n < 4; ++n) {
            const int colb = cb + n * 16;
            f32x4 v = acc[m][n];
            if (BIAS) {
                f32x4 bi = *reinterpret_cast<const f32x4*>(&bias[colb]);
                v += bi;
            }
            if (OUTF32) {
                *reinterpret_cast<f32x4*>(&((float*)Cp)[(size_t)row * Nld + colb]) = v;
            } else {
                short4 o;
                o.x = (short)f2b(v[0]); o.y = (short)f2b(v[1]);
                o.z = (short)f2b(v[2]); o.w = (short)f2b(v[3]);
                *reinterpret_cast<short4*>(&((short*)Cp)[(size_t)row * Nld + colb]) = o;
            }
        }
    }
}

// ---------------------------------------------------------------------------
// v cols of qkvb (bf16, col offset 1024) -> Vt bf16 [b][d][n]
// ---------------------------------------------------------------------------
__global__ __launch_bounds__(256)
void cvt_vt(const short* __restrict__ qkvb, short* __restrict__ Vt)
{
    __shared__ short t[64][72];
    const int b = blockIdx.z, n0 = blockIdx.x * 64, d0 = blockIdx.y * 64;
    const int tid = threadIdx.x;
    const short* src = qkvb + (size_t)(b * N_ + n0) * DQKV + 2 * DI + d0;
    #pragma unroll
    for (int q = 0; q < 2; ++q) {
        int s = tid + q * 256;
        int n = s >> 3, d8 = (s & 7) * 8;
        bf16x8 v = *reinterpret_cast<const bf16x8*>(&src[(size_t)n * DQKV + d8]);
        #pragma unroll
        for (int e = 0; e < 8; ++e) t[n][d8 + e] = v[e];
    }
    __syncthreads();
    short* dst = Vt + (size_t)b * DI * N_;
    #pragma unroll
    for (int q = 0; q < 2; ++q) {
        int s = tid + q * 256;
        int d = s >> 3, n8 = (s & 7) * 8;
        bf16x8 v;
        #pragma unroll
        for (int e = 0; e < 8; ++e) v[e] = t[n8 + e][d];
        *reinterpret_cast<bf16x8*>(&dst[(size_t)(d0 + d) * N_ + n0 + n8]) = v;
    }
}

// ---------------------------------------------------------------------------
// sim = q k^T * scale + prev, causal-masked, with fused per-128-block softmax
// partials -> Pm/Pl [b][jT][i].  Q/K staged via global_load_lds (no staging
// registers -> low VGPR, high residency).  grid: (N/128 j, N/128 i, B)
// ---------------------------------------------------------------------------
__global__ __launch_bounds__(256)
void sim_mfma(const short* __restrict__ qkvb, const float* __restrict__ prev,
              float* __restrict__ sim, float* __restrict__ Pm, float* __restrict__ Pl)
{
    const int b  = blockIdx.z;
    const int i0 = blockIdx.y * 128;
    const int j0 = blockIdx.x * 128;
    const int tid = threadIdx.x;
    float* simb = sim + (size_t)b * N_ * N_;

    if (j0 > i0 + 127) {                    // fully-masked: fill (no partials)
        const float4 m4 = make_float4(kNegMax, kNegMax, kNegMax, kNegMax);
        #pragma unroll
        for (int l = 0; l < 16; ++l) {
            int idx = tid + l * 256;
            int r = idx >> 5, c = (idx & 31) * 4;
            *reinterpret_cast<float4*>(&simb[(size_t)(i0 + r) * N_ + (j0 + c)]) = m4;
        }
        return;
    }

    __shared__ short Qs[128 * 64];
    __shared__ short Ks[128 * 64];
    __shared__ float wm[2][128], wl[2][128];
    const short* qb = qkvb + (size_t)(b * N_ + i0) * DQKV;
    const short* kb = qkvb + (size_t)(b * N_ + j0) * DQKV + DI;
    const int lane = tid & 63, wid = tid >> 6;
    const int wr = (wid >> 1) * 64, wc = (wid & 1) * 64;
    f32x4 acc[4][4] = {};

    for (int kt = 0; kt < 8; ++kt) {
        gstage_tile(Qs, qb, DQKV, kt * 64);
        gstage_tile(Ks, kb, DQKV, kt * 64);
        __syncthreads();                      // drains the gload_lds queue
        #pragma unroll
        for (int kk = 0; kk < 2; ++kk) {
            bf16x8 a[4], bb[4];
            #pragma unroll
            for (int m = 0; m < 4; ++m) a[m] = ld_frag(Qs, wr + m * 16, kk);
            #pragma unroll
            for (int n = 0; n < 4; ++n) bb[n] = ld_frag(Ks, wc + n * 16, kk);
            #pragma unroll
            for (int m = 0; m < 4; ++m)
                #pragma unroll
                for (int n = 0; n < 4; ++n)   // SWAPPED
                    acc[m][n] = __builtin_amdgcn_mfma_f32_16x16x32_bf16(bb[n], a[m], acc[m][n], 0, 0, 0);
        }
        __syncthreads();
    }
    const float* prevb = prev + (size_t)b * N_ * N_;
    const int ib = i0 + wr + (lane & 15);
    const int jb = j0 + wc + (lane >> 4) * 4;
    const int wcIdx = wid & 1;
    #pragma unroll
    for (int m = 0; m < 4; ++m) {
        const int row = ib + m * 16;
        float mx = -FLT_MAX;
        f32x4 ovals[4];
        #pragma unroll
        for (int n = 0; n < 4; ++n) {
            const int colb = jb + n * 16;
            f32x4 p = *reinterpret_cast<const f32x4*>(&prevb[(size_t)row * N_ + colb]);
            f32x4 o;
            #pragma unroll
            for (int reg = 0; reg < 4; ++reg)
                o[reg] = (colb + reg <= row) ? fmaf(acc[m][n][reg], kScale, p[reg]) : kNegMax;
            *reinterpret_cast<f32x4*>(&simb[(size_t)row * N_ + colb]) = o;
            ovals[n] = o;
            #pragma unroll
            for (int reg = 0; reg < 4; ++reg) mx = fmaxf(mx, o[reg]);
        }
        mx = fmaxf(mx, __shfl_xor(mx, 16));
        mx = fmaxf(mx, __shfl_xor(mx, 32));
        float s = 0.f;
        #pragma unroll
        for (int n = 0; n < 4; ++n)
            #pragma unroll
            for (int reg = 0; reg < 4; ++reg) s += __expf(ovals[n][reg] - mx);
        s += __shfl_xor(s, 16);
        s += __shfl_xor(s, 32);
        if ((lane >> 4) == 0) {
            int rr = wr + m * 16 + (lane & 15);
            wm[wcIdx][rr] = mx;
            wl[wcIdx][rr] = s;
        }
    }
    __syncthreads();
    if (tid < 128) {
        float m0 = wm[0][tid], m1 = wm[1][tid];
        float l0 = wl[0][tid], l1 = wl[1][tid];
        float M, L;
        if (m1 <= -1.0e38f) { M = m0; L = l0; }
        else {
            M = fmaxf(m0, m1);
            L = l0 * __expf(m0 - M) + l1 * __expf(m1 - M);
        }
        size_t slot = ((size_t)b * 32 + (j0 >> 7)) * N_ + i0 + tid;
        Pm[slot] = M;
        Pl[slot] = L;
    }
}

// ---------------------------------------------------------------------------
// Merge per-block partials into rowM / rowInv.
// ---------------------------------------------------------------------------
__global__ __launch_bounds__(256)
void merge_stats(const float* __restrict__ Pm, const float* __restrict__ Pl,
                 float* __restrict__ rowM, float* __restrict__ rowInv)
{
    int gid = blockIdx.x * 256 + threadIdx.x;        // 0..16383
    int b = gid >> 12, i = gid & (N_ - 1);
    int nt = (i >> 7) + 1;
    const float* pm = Pm + (size_t)b * 32 * N_ + i;
    const float* pl = Pl + (size_t)b * 32 * N_ + i;
    float M = -FLT_MAX;
    for (int t = 0; t < nt; ++t) M = fmaxf(M, pm[(size_t)t * N_]);
    float L = 0.f;
    for (int t = 0; t < nt; ++t) L += pl[(size_t)t * N_] * __expf(pm[(size_t)t * N_] - M);
    rowM[gid] = M;
    rowInv[gid] = 1.0f / L;
}

// ---------------------------------------------------------------------------
// Two-pass PV: out0b = softmax(sim) @ v with precomputed (M, 1/L).
// Block = 64 i x 256 d, 4 waves along d.  Register double-buffered prefetch.
// LPT grid: biggest i-tiles first.
// ---------------------------------------------------------------------------
__global__ __launch_bounds__(256)
void attn_v2(const float* __restrict__ sim, const short* __restrict__ Vt,
             const float* __restrict__ rowM, const float* __restrict__ rowInv,
             short* __restrict__ out0b)
{
    const int g = blockIdx.x;                 // 0..511, LPT order
    const int iT = 63 - (g >> 3);
    const int b = (g >> 1) & 3, dchunk = g & 1;
    const int i0 = iT * 64, d0 = dchunk * 256;
    const int tid = threadIdx.x;
    const int lane = tid & 63, wid = tid >> 6;
    const int wd = wid * 64;

    __shared__ short Ps[64 * 64];
    __shared__ short Vs[256 * 64];
    __shared__ float rm[64], ri[64];
    if (tid < 64) {
        rm[tid] = rowM[b * N_ + i0 + tid];
        ri[tid] = rowInv[b * N_ + i0 + tid];
    }
    __syncthreads();

    const float* simb = sim + (size_t)b * N_ * N_ + (size_t)i0 * N_;
    const short* vtb  = Vt + (size_t)b * DI * N_ + (size_t)d0 * N_;
    const int pr = tid >> 2, pc = (tid & 3) * 16;
    const float pmr = rm[pr], pir = ri[pr];
    f32x4 acc[4][4] = {};
    const int nk = iT + 1;

    f32x4  svA[4]; bf16x8 vvA[8];
    {
        const float* p = simb + (size_t)pr * N_ + pc;
        #pragma unroll
        for (int q = 0; q < 4; ++q) svA[q] = *reinterpret_cast<const f32x4*>(p + q * 4);
        const short* vp = vtb + (size_t)tid * N_;
        #pragma unroll
        for (int q = 0; q < 8; ++q) vvA[q] = *reinterpret_cast<const bf16x8*>(vp + q * 8);
    }
    for (int kt = 0; kt < nk; ++kt) {
        f32x4  svB[4]; bf16x8 vvB[8];
        const bool more = (kt + 1 < nk);
        if (more) {
            const float* p = simb + (size_t)pr * N_ + (kt + 1) * 64 + pc;
            #pragma unroll
            for (int q = 0; q < 4; ++q) svB[q] = *reinterpret_cast<const f32x4*>(p + q * 4);
            const short* vp = vtb + (size_t)tid * N_ + (kt + 1) * 64;
            #pragma unroll
            for (int q = 0; q < 8; ++q) vvB[q] = *reinterpret_cast<const bf16x8*>(vp + q * 8);
        }
        bf16x8 w0, w1;
        #pragma unroll
        for (int q = 0; q < 2; ++q)
            #pragma unroll
            for (int e = 0; e < 4; ++e) {
                w0[q * 4 + e] = (short)f2b(__expf(svA[q][e] - pmr) * pir);
                w1[q * 4 + e] = (short)f2b(__expf(svA[2 + q][e] - pmr) * pir);
            }
        {
            int sb = (tid & 3) * 2;
            *reinterpret_cast<bf16x8*>(&Ps[pr * 64 + ((sb    ) ^ (pr & 7)) * 8]) = w0;
            *reinterpret_cast<bf16x8*>(&Ps[pr * 64 + ((sb + 1) ^ (pr & 7)) * 8]) = w1;
        }
        #pragma unroll
        for (int q = 0; q < 8; ++q)
            *reinterpret_cast<bf16x8*>(&Vs[tid * 64 + (q ^ (tid & 7)) * 8]) = vvA[q];
        __syncthreads();
        #pragma unroll
        for (int kk = 0; kk < 2; ++kk) {
            bf16x8 a[4], bb[4];
            #pragma unroll
            for (int m = 0; m < 4; ++m) a[m] = ld_frag(Ps, m * 16, kk);
            #pragma unroll
            for (int n = 0; n < 4; ++n) bb[n] = ld_frag(Vs, wd + n * 16, kk);
            #pragma unroll
            for (int m = 0; m < 4; ++m)
                #pragma unroll
                for (int n = 0; n < 4; ++n)
                    acc[m][n] = __builtin_amdgcn_mfma_f32_16x16x32_bf16(bb[n], a[m], acc[m][n], 0, 0, 0);
        }
        __syncthreads();
        if (more) {
            #pragma unroll
            for (int q = 0; q < 4; ++q) svA[q] = svB[q];
            #pragma unroll
            for (int q = 0; q < 8; ++q) vvA[q] = vvB[q];
        }
    }
    #pragma unroll
    for (int m = 0; m < 4; ++m) {
        const int i = i0 + m * 16 + (lane & 15);
        #pragma unroll
        for (int n = 0; n < 4; ++n) {
            const int db = d0 + wd + n * 16 + (lane >> 4) * 4;
            short4 o;
            o.x = (short)f2b(acc[m][n][0]);
            o.y = (short)f2b(acc[m][n][1]);
            o.z = (short)f2b(acc[m][n][2]);
            o.w = (short)f2b(acc[m][n][3]);
            *reinterpret_cast<short4*>(&out0b[(size_t)(b * N_ + i) * DI + db]) = o;
        }
    }
}

// ---------------------------------------------------------------------------
extern "C" void kernel_launch(void* const* d_in, const int* in_sizes, int n_in,
                              void* d_out, int out_size, void* d_ws, size_t ws_size,
                              hipStream_t stream)
{
    (void)in_sizes; (void)n_in; (void)out_size; (void)ws_size;
    const float* x    = (const float*)d_in[0];
    const float* prev = (const float*)d_in[1];
    const float* Wqkv = (const float*)d_in[2];
    const float* Wout = (const float*)d_in[3];
    const float* bout = (const float*)d_in[4];

    float* out = (float*)d_out;                        // [4,4096,512]
    float* sim = out + (size_t)MTOT * DOUTD;           // [4,4096,4096]

    // workspace (~90 MB)
    short* qkvb   = (short*)d_ws;                      // [16384][1536] bf16
    short* out0b  = qkvb + (size_t)MTOT * DQKV;        // [16384][512]  bf16
    short* Vt     = out0b + (size_t)MTOT * DI;         // [4][512][4096] bf16
    short* Wqkvt  = Vt + (size_t)MTOT * DI;            // [1536][512]
    short* Woutt  = Wqkvt + (size_t)DQKV * DIN;        // [512][512]
    float* Pm     = (float*)(Woutt + (size_t)DI * DOUTD);  // [4][32][4096]
    float* Pl     = Pm + (size_t)B_ * 32 * N_;             // [4][32][4096]
    float* rowM   = Pl + (size_t)B_ * 32 * N_;             // [16384]
    float* rowInv = rowM + MTOT;                           // [16384]

    // 0) weight transpose-converts (tiny)
    cvt_wt<<<dim3(DQKV / 64, DIN / 64), 256, 0, stream>>>(Wqkv, Wqkvt, DIN, DQKV);
    cvt_wt<<<dim3(DOUTD / 64, DI / 64), 256, 0, stream>>>(Wout, Woutt, DI, DOUTD);

    // 1) qkvb = bf16(x) @ bf16(Wqkv)   (MFMA; B via global_load_lds)
    gemm_mfma<DIN, true, false, false><<<dim3(DQKV / 128, MTOT / 128), 256, 0, stream>>>(
        x, Wqkvt, nullptr, qkvb, DQKV);

    // 2) v -> Vt transposed
    cvt_vt<<<dim3(N_ / 64, DI / 64, B_), 256, 0, stream>>>(qkvb, Vt);

    // 3) sim = q k^T * scale + prev + fused softmax partials (gload_lds staging)
    sim_mfma<<<dim3(N_ / 128, N_ / 128, B_), 256, 0, stream>>>(qkvb, prev, sim, Pm, Pl);

    // 4) merge partials -> rowM, rowInv
    merge_stats<<<dim3(MTOT / 256), 256, 0, stream>>>(Pm, Pl, rowM, rowInv);

    // 5) out0b = softmax(sim) @ v   (two-pass PV, prefetched, LPT order)
    attn_v2<<<dim3(512), 256, 0, stream>>>(sim, Vt, rowM, rowInv, out0b);

    // 6) out = out0b @ Wout + bout  (MFMA, A+B via global_load_lds, f32 out)
    gemm_mfma<DI, false, true, true><<<dim3(DOUTD / 128, MTOT / 128), 256, 0, stream>>>(
        out0b, Woutt, bout, out, DOUTD);
}